// Round 3
// baseline (76.406 us; speedup 1.0000x reference)
//
#include <hip/hip_runtime.h>

// Quanvolution: 802816 independent 4-qubit sims, one thread per patch.
// Gates are SU(2): U = [[a, b], [-conj(b), conj(a)]].
// State as 16 x v2f (packed re/im) -> v_pk_fma_f32 butterflies (4 pk-fma per output).
// launch_bounds(256,4) caps VGPR at 128 for >=4 waves/SIMD.

typedef float v2f __attribute__((ext_vector_type(2)));

__device__ __forceinline__ v2f pkfma(v2f a, v2f b, v2f c) {
    return __builtin_elementwise_fma(a, b, c);
}
// complex multiply, packed: r = a*b (complex)
__device__ __forceinline__ v2f pkcmul(v2f a, v2f b) {
    const v2f t = a.yy * b.yx;                  // {ay*by, ay*bx}
    return pkfma(a.xx, b, (v2f){-t.x, t.y});    // {ax*bx - ay*by, ax*by + ay*bx}
}
// SU(2) butterfly: x0' = a*x0 + b*x1 ; x1' = -conj(b)*x0 + conj(a)*x1
// A={ax,ax} An={-ay,ay} B={bx,bx} Bn={-by,by}
__device__ __forceinline__ void bfly(v2f A, v2f An, v2f B, v2f Bn, v2f& x0, v2f& x1) {
    const v2f x0s = x0.yx, x1s = x1.yx;
    const v2f y0 = pkfma(A, x0, pkfma(An, x0s, pkfma(B, x1, Bn * x1s)));
    const v2f y1 = pkfma(-B, x0, pkfma(Bn, x0s, pkfma(A, x1, (-An) * x1s)));
    x0 = y0; x1 = y1;
}

__global__ __launch_bounds__(256, 4) void quanv_kernel(
        const float* __restrict__ x,       // (4096, 28, 28)
        const float* __restrict__ params,  // (2, 4, 3)
        float* __restrict__ out)           // (4096, 196*4)
{
    __shared__ float4 Gs[8];     // per gate: {ax, ay, bx, by}
    __shared__ v2f    G2[8][4];  // per gate: A, An, B, Bn (packed splat pairs)
    const int t = threadIdx.x;
    if (t < 8) {
        const float* p = params + t * 3;
        const float a = 0.5f * p[0], b = 0.5f * p[1], c = 0.5f * p[2];
        const float sa = __sinf(a), ca = __cosf(a);
        const float sb = __sinf(b), cb = __cosf(b);
        const float sc = __sinf(c), cc = __cosf(c);
        const float ax = cc*ca*cb + sc*sa*sb;
        const float ay = -(cc*ca*sb + sc*sa*cb);
        const float bx = sc*ca*sb - cc*sa*cb;
        const float by = cc*sa*sb - sc*ca*cb;
        Gs[t] = make_float4(ax, ay, bx, by);
        G2[t][0] = (v2f){ax, ax};
        G2[t][1] = (v2f){-ay, ay};
        G2[t][2] = (v2f){bx, bx};
        G2[t][3] = (v2f){-by, by};
    }
    __syncthreads();

    const int gid = blockIdx.x * 256 + t;          // patch id: n*196 + r*14 + c
    const int n = gid / 196;
    const int p = gid - n * 196;
    const int r = p / 14;
    const int c = p - r * 14;

    const float* xb = x + n * 784 + r * 56 + c * 2;   // even offset -> 8B aligned
    const float2 top = *(const float2*)(xb);
    const float2 bot = *(const float2*)(xb + 28);

    // per-wire: RY(pixel)|0> = (cw, sw), then layer-1 gate applied on the 2-vector
    float pw[4] = {0.5f * top.x, 0.5f * top.y, 0.5f * bot.x, 0.5f * bot.y};
    v2f wv[4][2];
#pragma unroll
    for (int w = 0; w < 4; ++w) {
        const float cw = __cosf(pw[w]);
        const float sw = __sinf(pw[w]);
        const float4 g = Gs[w];
        wv[w][0] = (v2f){fmaf(g.z, sw, g.x * cw),  fmaf(g.w, sw, g.y * cw)};
        wv[w][1] = (v2f){fmaf(g.x, sw, -g.z * cw), fmaf(-g.y, sw, g.w * cw)};
    }

    // tensor product: s[a*8+b*4+c*2+d] = wv0[a]*wv1[b]*wv2[c]*wv3[d]
    v2f ab[4], cd[4];
#pragma unroll
    for (int i = 0; i < 2; ++i)
#pragma unroll
        for (int j = 0; j < 2; ++j) {
            ab[i * 2 + j] = pkcmul(wv[0][i], wv[1][j]);
            cd[i * 2 + j] = pkcmul(wv[2][i], wv[3][j]);
        }
    v2f s[16];
#pragma unroll
    for (int hi = 0; hi < 4; ++hi)
#pragma unroll
        for (int lo = 0; lo < 4; ++lo)
            s[hi * 4 + lo] = pkcmul(ab[hi], cd[lo]);

    // layer-1 CNOT ring: (0,1),(1,2),(2,3),(3,0) — register renames
#pragma unroll
    for (int k = 0; k < 4; ++k) {
        const int bc = 8 >> k;
        const int bt = 8 >> ((k + 1) & 3);
#pragma unroll
        for (int i = 0; i < 16; ++i)
            if ((i & bc) && !(i & bt)) { const v2f tmp = s[i]; s[i] = s[i | bt]; s[i | bt] = tmp; }
    }

    // layer-2 single-qubit gates: packed butterflies
#pragma unroll
    for (int w = 0; w < 4; ++w) {
        const int g = 4 + w;
        const v2f A = G2[g][0], An = G2[g][1], B = G2[g][2], Bn = G2[g][3];
        const int bit = 8 >> w;
#pragma unroll
        for (int i = 0; i < 16; ++i) {
            if (i & bit) continue;
            bfly(A, An, B, Bn, s[i], s[i | bit]);
        }
    }

    // layer-2 CNOT ring
#pragma unroll
    for (int k = 0; k < 4; ++k) {
        const int bc = 8 >> k;
        const int bt = 8 >> ((k + 1) & 3);
#pragma unroll
        for (int i = 0; i < 16; ++i)
            if ((i & bc) && !(i & bt)) { const v2f tmp = s[i]; s[i] = s[i | bt]; s[i | bt] = tmp; }
    }

    // <Z_w>: i = a*8+b*4+c*2+d, wire0=a ... wire3=d
    float pr[16];
#pragma unroll
    for (int i = 0; i < 16; ++i)
        pr[i] = fmaf(s[i].x, s[i].x, s[i].y * s[i].y);

    const float t00 = pr[0] + pr[1] + pr[2]  + pr[3];
    const float t01 = pr[4] + pr[5] + pr[6]  + pr[7];
    const float t10 = pr[8] + pr[9] + pr[10] + pr[11];
    const float t11 = pr[12] + pr[13] + pr[14] + pr[15];
    const float e0 = (t00 + t01) - (t10 + t11);
    const float e1 = (t00 - t01) + (t10 - t11);

    const float u00 = pr[0] + pr[4] + pr[8]  + pr[12];
    const float u01 = pr[1] + pr[5] + pr[9]  + pr[13];
    const float u10 = pr[2] + pr[6] + pr[10] + pr[14];
    const float u11 = pr[3] + pr[7] + pr[11] + pr[15];
    const float e2 = (u00 + u01) - (u10 + u11);
    const float e3 = (u00 - u01) + (u10 - u11);

    *(float4*)(out + gid * 4) = make_float4(e0, e1, e2, e3);
}

extern "C" void kernel_launch(void* const* d_in, const int* in_sizes, int n_in,
                              void* d_out, int out_size, void* d_ws, size_t ws_size,
                              hipStream_t stream) {
    const float* x      = (const float*)d_in[0];   // 4096*28*28
    const float* params = (const float*)d_in[1];   // 2*4*3
    float* out = (float*)d_out;                    // 4096*784

    const int npatch = 4096 * 196;                 // 802816, divisible by 256
    quanv_kernel<<<npatch / 256, 256, 0, stream>>>(x, params, out);
}

// Round 4
// 71.842 us; speedup vs baseline: 1.0635x; 1.0635x over previous
//
#include <hip/hip_runtime.h>

// Quanvolution: 802816 independent 4-qubit sims.
// Structure: per-thread product state (layer-1 gates folded per-wire, fp32 VALU),
// then the ENTIRE remaining evolution M = P2 * (u4(x)u5(x)u6(x)u7) * P1 is one
// shared 16x16 complex matrix -> real 32x32 f16 matrix W, applied to all patch
// states via MFMA f32_16x16x32_f16 (per wave: 64 patches = 4 row-groups x 2
// output halves = 8 MFMAs). Epilogue: |amp|^2 per lane, LDS transpose, sign sums.
// CNOT-ring permutation tables are compile-time (verified by hand-simulating the
// swap code: e.g. |0010> -> |1011>, idx1[11]=2).

typedef _Float16 f16;
typedef _Float16 half8 __attribute__((ext_vector_type(8)));
typedef float f4 __attribute__((ext_vector_type(4)));

__device__ __forceinline__ float2 cmulf(float2 a, float2 b) {
    return make_float2(fmaf(a.x, b.x, -(a.y * b.y)),
                       fmaf(a.x, b.y,   a.y * b.x));
}

// pack two f32 -> one f16x2 dword, bitcast to float for float4 assembly
#define PK2(a, b) __builtin_bit_cast(float, __builtin_amdgcn_cvt_pkrtz((a), (b)))

__global__ __launch_bounds__(256, 4) void quanv_kernel(
        const float* __restrict__ x,       // (4096, 28, 28)
        const float* __restrict__ params,  // (2, 4, 3)
        float* __restrict__ out)           // (4096, 196*4)
{
    __shared__ float4 Gs[8];                         // SU(2) gates: {ax, ay, bx, by}
    __shared__ __align__(16) f16 Wt[32][40];         // Wt[n][k] = B[k][n], rows padded to 80B
    __shared__ __align__(16) unsigned char SB[4][5120]; // per-wave: states (f16, 80B/patch) then pr (f32, 80B/patch)

    const int t = threadIdx.x;

    // ---- SU(2) gate params: U = RX(c) RZ(b) RY(a) = [[a, b], [-conj(b), conj(a)]] ----
    if (t < 8) {
        const float* p = params + t * 3;
        const float a = 0.5f * p[0], b = 0.5f * p[1], c = 0.5f * p[2];
        const float sa = __sinf(a), ca = __cosf(a);
        const float sb = __sinf(b), cb = __cosf(b);
        const float sc = __sinf(c), cc = __cosf(c);
        const float ax = cc*ca*cb + sc*sa*sb;
        const float ay = -(cc*ca*sb + sc*sa*cb);
        const float bx = sc*ca*sb - cc*sa*cb;
        const float by = cc*sa*sb - sc*ca*cb;
        Gs[t] = make_float4(ax, ay, bx, by);
    }
    __syncthreads();

    // ---- build W (32x32 real embedding of M = P2*U2*P1), one entry of M per thread ----
    {
        // CNOT-ring permutation (both layers identical), nibble-packed:
        // idx1 = [0,13,3,14,6,11,5,8,12,1,15,2,10,7,9,4]; inv1 = its inverse
        const unsigned long long IDX1P = 0x497a2f1c85b6e3d0ULL;
        const unsigned long long INV1P = 0xa3185ce7d46f2b90ULL;
        const int i = t >> 4;      // output amp index
        const int m = t & 15;      // input amp index
        const int j = (int)((IDX1P >> (i * 4)) & 15);   // row into U2 (P2 fold)
        const int k = (int)((INV1P >> (m * 4)) & 15);   // col into U2 (P1 fold)
        float2 e = make_float2(1.f, 0.f);               // M[i][m] = prod_w u_w[j_w][k_w]
#pragma unroll
        for (int w = 0; w < 4; ++w) {
            const float4 g = Gs[4 + w];
            const int jb = (j >> (3 - w)) & 1;
            const int kb = (k >> (3 - w)) & 1;
            // u[0][0]=(ax,ay) u[0][1]=(bx,by) u[1][0]=(-bx,by) u[1][1]=(ax,-ay)
            const float ux = jb ? (kb ?  g.x : -g.z) : (kb ? g.z : g.x);
            const float uy = jb ? (kb ? -g.y :  g.w) : (kb ? g.w : g.y);
            e = cmulf(e, make_float2(ux, uy));
        }
        // real embedding, stored transposed: Wt[n][k] = B[k][n]
        // out_re[i]: B[m][i]=Mre, B[16+m][i]=-Mim ; out_im[i]: B[m][16+i]=Mim, B[16+m][16+i]=Mre
        Wt[i][m]           = (f16)e.x;
        Wt[i][16 + m]      = (f16)(-e.y);
        Wt[16 + i][m]      = (f16)e.y;
        Wt[16 + i][16 + m] = (f16)e.x;
    }

    // ---- per-patch product state after layer-1 gates + input RY ----
    const int gid = blockIdx.x * 256 + t;          // patch id: n*196 + r*14 + c
    const int n = gid / 196;
    const int p = gid - n * 196;
    const int r = p / 14;
    const int c = p - r * 14;

    const float* xb = x + n * 784 + r * 56 + c * 2;   // even offset -> 8B aligned
    const float2 top = *(const float2*)(xb);
    const float2 bot = *(const float2*)(xb + 28);

    float pw[4] = {0.5f * top.x, 0.5f * top.y, 0.5f * bot.x, 0.5f * bot.y};
    float2 wv[4][2];
#pragma unroll
    for (int w = 0; w < 4; ++w) {
        const float cw = __cosf(pw[w]);
        const float sw = __sinf(pw[w]);
        const float4 g = Gs[w];
        wv[w][0] = make_float2(fmaf(g.z, sw, g.x * cw),  fmaf(g.w, sw, g.y * cw));
        wv[w][1] = make_float2(fmaf(g.x, sw, -g.z * cw), fmaf(-g.y, sw, g.w * cw));
    }

    float2 ab[4], cd[4];
#pragma unroll
    for (int i = 0; i < 2; ++i)
#pragma unroll
        for (int j = 0; j < 2; ++j) {
            ab[i * 2 + j] = cmulf(wv[0][i], wv[1][j]);
            cd[i * 2 + j] = cmulf(wv[2][i], wv[3][j]);
        }
    float2 s[16];
#pragma unroll
    for (int hi = 0; hi < 4; ++hi)
#pragma unroll
        for (int lo = 0; lo < 4; ++lo)
            s[hi * 4 + lo] = cmulf(ab[hi], cd[lo]);

    // ---- pack state to f16 vector v[32] = [re0..re15, im0..im15], write to LDS ----
    const int l   = t & 63;          // lane
    const int wid = t >> 6;          // wave id
    const int q   = l >> 4;          // quad
    const int c16 = l & 15;

    f16* st = (f16*)(SB[wid] + l * 80);
    const float4 r0 = make_float4(PK2(s[0].x, s[1].x),  PK2(s[2].x, s[3].x),
                                  PK2(s[4].x, s[5].x),  PK2(s[6].x, s[7].x));
    const float4 r1 = make_float4(PK2(s[8].x, s[9].x),  PK2(s[10].x, s[11].x),
                                  PK2(s[12].x, s[13].x), PK2(s[14].x, s[15].x));
    const float4 r2 = make_float4(PK2(s[0].y, s[1].y),  PK2(s[2].y, s[3].y),
                                  PK2(s[4].y, s[5].y),  PK2(s[6].y, s[7].y));
    const float4 r3 = make_float4(PK2(s[8].y, s[9].y),  PK2(s[10].y, s[11].y),
                                  PK2(s[12].y, s[13].y), PK2(s[14].y, s[15].y));
    *(float4*)(st)      = r0;
    *(float4*)(st + 8)  = r1;
    *(float4*)(st + 16) = r2;
    *(float4*)(st + 24) = r3;

    __syncthreads();   // Wt ready (state region is per-wave, needs no barrier)

    // ---- MFMA: D[patch][j] = sum_k state[patch][k] * B[k][j] ----
    // A-frag: lane holds A[row=lane&15][k=quad*8+j] ; B-frag: B[k=quad*8+j][n=lane&15]
    const half8 b0 = *(const half8*)&Wt[c16][q * 8];        // output cols 0..15  (re)
    const half8 b1 = *(const half8*)&Wt[16 + c16][q * 8];   // output cols 16..31 (im)
    const f4 zf4 = {0.f, 0.f, 0.f, 0.f};
    f4 d0[4], d1[4];
#pragma unroll
    for (int m = 0; m < 4; ++m) {
        const half8 am = *(const half8*)((const f16*)(SB[wid] + (m * 16 + c16) * 80) + q * 8);
        d0[m] = __builtin_amdgcn_mfma_f32_16x16x32_f16(am, b0, zf4, 0, 0, 0);
        d1[m] = __builtin_amdgcn_mfma_f32_16x16x32_f16(am, b1, zf4, 0, 0, 0);
    }

    // ---- |amp|^2: lane holds re (d0) and im (d1) of amp c16 for 16 patches ----
    // C/D layout (m89): col=lane&15, row=quad*4+reg -> patch_local = m*16 + q*4 + reg
    float* prb = (float*)SB[wid];   // reuse per-wave region: [64 patches][20 floats, 80B rows]
#pragma unroll
    for (int m = 0; m < 4; ++m)
#pragma unroll
        for (int reg = 0; reg < 4; ++reg) {
            const float pv = fmaf(d0[m][reg], d0[m][reg], d1[m][reg] * d1[m][reg]);
            prb[(m * 16 + q * 4 + reg) * 20 + c16] = pv;   // 2-way banks: free
        }

    // read back own patch's 16 probabilities (same wave wrote them; DS is in-order)
    const float4 p0 = *(const float4*)(prb + l * 20);       // amps 0..3
    const float4 p1 = *(const float4*)(prb + l * 20 + 4);   // amps 4..7
    const float4 p2 = *(const float4*)(prb + l * 20 + 8);   // amps 8..11
    const float4 p3 = *(const float4*)(prb + l * 20 + 12);  // amps 12..15

    // <Z_w>: amp index i = a*8+b*4+c*2+d, wire0=a ... wire3=d
    const float t00 = p0.x + p0.y + p0.z + p0.w;
    const float t01 = p1.x + p1.y + p1.z + p1.w;
    const float t10 = p2.x + p2.y + p2.z + p2.w;
    const float t11 = p3.x + p3.y + p3.z + p3.w;
    const float e0 = (t00 + t01) - (t10 + t11);
    const float e1 = (t00 - t01) + (t10 - t11);

    const float u00 = p0.x + p1.x + p2.x + p3.x;
    const float u01 = p0.y + p1.y + p2.y + p3.y;
    const float u10 = p0.z + p1.z + p2.z + p3.z;
    const float u11 = p0.w + p1.w + p2.w + p3.w;
    const float e2 = (u00 + u01) - (u10 + u11);
    const float e3 = (u00 - u01) + (u10 - u11);

    *(float4*)(out + gid * 4) = make_float4(e0, e1, e2, e3);
}

extern "C" void kernel_launch(void* const* d_in, const int* in_sizes, int n_in,
                              void* d_out, int out_size, void* d_ws, size_t ws_size,
                              hipStream_t stream) {
    const float* x      = (const float*)d_in[0];   // 4096*28*28
    const float* params = (const float*)d_in[1];   // 2*4*3
    float* out = (float*)d_out;                    // 4096*784

    const int npatch = 4096 * 196;                 // 802816, divisible by 256
    quanv_kernel<<<npatch / 256, 256, 0, stream>>>(x, params, out);
}